// Round 15
// baseline (56.202 us; speedup 1.0000x reference)
//
#include <hip/hip_runtime.h>
#include <hip/hip_bf16.h>
#include <math.h>

#define B_    8
#define N_    2048
#define DIM_  64
#define H_    4
#define HD_   16
#define HID_  128
#define NROWS (B_ * N_)          // 16384
#define KVB   64
#define QSCALE (0.25f * 1.4426950408889634f)   // hd^-0.5 * log2(e)

typedef float    f32x4 __attribute__((ext_vector_type(4)));
typedef __fp16   hfx2  __attribute__((ext_vector_type(2)));
typedef _Float16 f16x4 __attribute__((ext_vector_type(4)));
typedef _Float16 f16x8 __attribute__((ext_vector_type(8)));

#define MFMA16(a, b, c) __builtin_amdgcn_mfma_f32_16x16x16f16((a), (b), (c), 0, 0, 0)

__device__ __forceinline__ float ex2(float x) {
#if __has_builtin(__builtin_amdgcn_exp2f)
    return __builtin_amdgcn_exp2f(x);
#else
    return exp2f(x);
#endif
}

// packed-f16 dot2 with f32 accumulate (l-sum against ones)
#if __has_builtin(__builtin_amdgcn_fdot2)
#define DOT2ACC(A, B, C) __builtin_amdgcn_fdot2((A), (B), (C), false)
#else
#define DOT2ACC(A, B, C) ((C) + (float)(A)[0] + (float)(A)[1])
#endif

// -------------------------------------------------------------------------
// Kernel 1 (MFMA, 512 threads, 64 rows/block, grid 256): r12 config
// (best measured). XCD-producer swizzle (batch b -> XCD b).
// -------------------------------------------------------------------------
__global__ __launch_bounds__(512) void k1_ln_qkv(
    const float* __restrict__ x, const float* __restrict__ clinic,
    const float* __restrict__ n1g, const float* __restrict__ n1b,
    const float* __restrict__ Wkv, const float* __restrict__ bkv,
    const float* __restrict__ Wq,  const float* __restrict__ bq,
    _Float16* __restrict__ Kd, _Float16* __restrict__ VTd,
    _Float16* __restrict__ Qd)
{
    __shared__ _Float16 WkvT[128][68];   // [col][k]
    __shared__ _Float16 WqT [64][68];
    __shared__ _Float16 xnT [64][68];    // [row][k]
    __shared__ _Float16 cnT [64][68];

    const int tid  = threadIdx.x;
    const int lblk = (blockIdx.x & 7) * 32 + (blockIdx.x >> 3);
    const int row0 = lblk * 64;

    #pragma unroll
    for (int i = tid; i < 2048; i += 512) {          // Wkv 64x128
        const float4 w = ((const float4*)Wkv)[i];
        const int e = i * 4, d = e >> 7, c = e & 127;
        WkvT[c + 0][d] = (_Float16)w.x;
        WkvT[c + 1][d] = (_Float16)w.y;
        WkvT[c + 2][d] = (_Float16)w.z;
        WkvT[c + 3][d] = (_Float16)w.w;
    }
    #pragma unroll
    for (int i = tid; i < 1024; i += 512) {          // Wq 64x64
        const float4 w = ((const float4*)Wq)[i];
        const int e = i * 4, d = e >> 6, c = e & 63;
        WqT[c + 0][d] = (_Float16)w.x;
        WqT[c + 1][d] = (_Float16)w.y;
        WqT[c + 2][d] = (_Float16)w.z;
        WqT[c + 3][d] = (_Float16)w.w;
    }

    {
        const int r = tid >> 4, s = tid & 15;
        const float4 gv = *(const float4*)(n1g + s * 4);
        const float4 bv = *(const float4*)(n1b + s * 4);
        #pragma unroll
        for (int it = 0; it < 2; ++it) {
            const int rl = it * 32 + r;
            const int rg = row0 + rl;
            float4 xv = *(const float4*)(x      + (size_t)rg * DIM_ + s * 4);
            float4 cv = *(const float4*)(clinic + (size_t)rg * DIM_ + s * 4);

            float xs = xv.x + xv.y + xv.z + xv.w;
            float cs = cv.x + cv.y + cv.z + cv.w;
            #pragma unroll
            for (int m = 1; m < 16; m <<= 1) {
                xs += __shfl_xor(xs, m);
                cs += __shfl_xor(cs, m);
            }
            const float xmu = xs * (1.f / 64.f);
            const float cmu = cs * (1.f / 64.f);
            float4 xd = make_float4(xv.x - xmu, xv.y - xmu, xv.z - xmu, xv.w - xmu);
            float4 cd = make_float4(cv.x - cmu, cv.y - cmu, cv.z - cmu, cv.w - cmu);

            float xq = xd.x * xd.x + xd.y * xd.y + xd.z * xd.z + xd.w * xd.w;
            float cq = cd.x * cd.x + cd.y * cd.y + cd.z * cd.z + cd.w * cd.w;
            #pragma unroll
            for (int m = 1; m < 16; m <<= 1) {
                xq += __shfl_xor(xq, m);
                cq += __shfl_xor(cq, m);
            }
            const float xinv = rsqrtf(xq * (1.f / 64.f) + 1e-5f);
            const float cinv = rsqrtf(cq * (1.f / 64.f) + 1e-5f);

            f16x4 xo, co;
            xo[0] = (_Float16)(xd.x * xinv * gv.x + bv.x);
            xo[1] = (_Float16)(xd.y * xinv * gv.y + bv.y);
            xo[2] = (_Float16)(xd.z * xinv * gv.z + bv.z);
            xo[3] = (_Float16)(xd.w * xinv * gv.w + bv.w);
            co[0] = (_Float16)(cd.x * cinv * gv.x + bv.x);
            co[1] = (_Float16)(cd.y * cinv * gv.y + bv.y);
            co[2] = (_Float16)(cd.z * cinv * gv.z + bv.z);
            co[3] = (_Float16)(cd.w * cinv * gv.w + bv.w);
            *(f16x4*)&xnT[rl][s * 4] = xo;
            *(f16x4*)&cnT[rl][s * 4] = co;
        }
    }
    __syncthreads();

    const int lane = tid & 63, wave = tid >> 6;
    const int col  = lane & 15;
    const int grp4 = (lane >> 4) * 4;
    const int rt   = wave & 3;
    const int half = wave >> 2;
    const int arow = rt * 16 + col;
    const f32x4 Z = {0.f, 0.f, 0.f, 0.f};

    f16x4 ax[4], ac[4];
    #pragma unroll
    for (int kt = 0; kt < 4; ++kt) {
        ax[kt] = *(const f16x4*)&xnT[arow][kt * 16 + grp4];
        ac[kt] = *(const f16x4*)&cnT[arow][kt * 16 + grp4];
    }

    const int rg0 = row0 + rt * 16 + grp4;
    const int b   = rg0 >> 11;
    const int n0  = rg0 & (N_ - 1);

    #pragma unroll
    for (int cti = 0; cti < 4; ++cti) {
        const int ct = half * 4 + cti;
        f32x4 acc = Z;
        #pragma unroll
        for (int kt = 0; kt < 4; ++kt) {
            const f16x4 bf = *(const f16x4*)&WkvT[ct * 16 + col][kt * 16 + grp4];
            acc = MFMA16(ax[kt], bf, acc);
        }
        const int c = ct * 16 + col;
        const float bias = bkv[c];
        const int hh = (c >> 4) & 3, dd = c & 15;
        if (c & 64) {
            f16x4 v4;
            #pragma unroll
            for (int r = 0; r < 4; ++r) v4[r] = (_Float16)(acc[r] + bias);
            *(f16x4*)(VTd + (((size_t)(b * H_ + hh)) * HD_ + dd) * N_ + n0) = v4;
        } else {
            #pragma unroll
            for (int r = 0; r < 4; ++r)
                Kd[(((size_t)(b * H_ + hh)) * N_ + n0 + r) * HD_ + dd] =
                    (_Float16)(acc[r] + bias);
        }
    }
    #pragma unroll
    for (int cti = 0; cti < 2; ++cti) {
        const int ct = half * 2 + cti;
        f32x4 acc = Z;
        #pragma unroll
        for (int kt = 0; kt < 4; ++kt) {
            const f16x4 bf = *(const f16x4*)&WqT[ct * 16 + col][kt * 16 + grp4];
            acc = MFMA16(ac[kt], bf, acc);
        }
        const int c = ct * 16 + col;
        const float bias = bq[c];
        const int hh = c >> 4, dd = c & 15;
        #pragma unroll
        for (int r = 0; r < 4; ++r)
            Qd[(((size_t)(b * H_ + hh)) * N_ + n0 + r) * HD_ + dd] =
                (_Float16)((acc[r] + bias) * QSCALE);
    }
}

// -------------------------------------------------------------------------
// Kernel 2: pure-register MFMA flash attention, round-15 = HIGH-TLP form:
// 2 q-frags/wave (halves live state), grid 2048 (8 blocks/CU),
// __launch_bounds__(256,6) -> target 6 waves/SIMD (vs 4 in r8-r13; the
// one regime never tested with the lean loop). 2-deep A/B prefetch,
// packed-f16 poly softmax, XCD alignment (batch = bid&7 = XCD) kept.
// -------------------------------------------------------------------------
#define K2_LOAD(KF, VF, T)                                                   \
    {                                                                        \
        _Pragma("unroll")                                                    \
        for (int sb = 0; sb < 4; ++sb) {                                     \
            KF[sb] = *(const f16x4*)(Kbh + koff + (T) * (KVB * HD_) +        \
                                     sb * (16 * HD_));                       \
            VF[sb] = *(const f16x4*)(Vbh + voff + (T) * KVB + sb * 16);      \
        }                                                                    \
    }

#define K2_PROC(KF, VF)                                                      \
    {                                                                        \
        const f32x4 Z = {0.f, 0.f, 0.f, 0.f};                                \
        _Pragma("unroll")                                                    \
        for (int qp = 0; qp < 2; ++qp) {                                     \
            f32x4 s[4];                                                      \
            _Pragma("unroll")                                                \
            for (int sb = 0; sb < 4; ++sb)                                   \
                s[sb] = MFMA16(KF[sb], qp ? qf1 : qf0, Z);                   \
            float pl = 0.f;                                                  \
            f16x4 pf[4];                                                     \
            _Pragma("unroll")                                                \
            for (int sb = 0; sb < 4; ++sb) {                                 \
                const hfx2 h01 = __builtin_amdgcn_cvt_pkrtz(s[sb][0],        \
                                                            s[sb][1]);       \
                const hfx2 h23 = __builtin_amdgcn_cvt_pkrtz(s[sb][2],        \
                                                            s[sb][3]);       \
                hfx2 p01 = h01 * PC3 + PC2;                                  \
                p01 = h01 * p01 + PC1;                                       \
                p01 = h01 * p01 + PC0;                                       \
                hfx2 p23 = h23 * PC3 + PC2;                                  \
                p23 = h23 * p23 + PC1;                                       \
                p23 = h23 * p23 + PC0;                                       \
                pl = DOT2ACC(p01, PC0, pl);                                  \
                pl = DOT2ACC(p23, PC0, pl);                                  \
                pf[sb] = (f16x4){(_Float16)p01[0], (_Float16)p01[1],         \
                                 (_Float16)p23[0], (_Float16)p23[1]};        \
            }                                                                \
            if (qp == 0) l0 += pl; else l1 += pl;                            \
            f32x4& o = qp ? o1 : o0;                                         \
            _Pragma("unroll")                                                \
            for (int sb = 0; sb < 4; ++sb)                                   \
                o = MFMA16(pf[sb], VF[sb], o);                               \
        }                                                                    \
    }

__global__ __launch_bounds__(256, 6) void k2_attn(
    const _Float16* __restrict__ Kd, const _Float16* __restrict__ VTd,
    const _Float16* __restrict__ Qd, float* __restrict__ O)
{
    __shared__ float smO[4][32][18];   // merge: [wave][q][hd+pad]
    __shared__ float smL[4][32];

    const int tid  = threadIdx.x;
    const int lane = tid & 63;
    const int wave = tid >> 6;
    const int col  = lane & 15;
    const int grp4 = (lane >> 4) * 4;

    // 2^s Taylor coefficients (packed f16)
    const hfx2 PC3 = {(__fp16)0.05550411f, (__fp16)0.05550411f};
    const hfx2 PC2 = {(__fp16)0.24022651f, (__fp16)0.24022651f};
    const hfx2 PC1 = {(__fp16)0.69314718f, (__fp16)0.69314718f};
    const hfx2 PC0 = {(__fp16)1.0f,        (__fp16)1.0f};

    // consumer swizzle: 2048 wgs, 256/XCD; batch = bid&7 = XCD
    const int wg = (blockIdx.x & 7) * 256 + (blockIdx.x >> 3);
    const int bh = wg >> 6;        // 0..31
    const int qt = wg & 63;        // 0..63

    const _Float16* Kbh = Kd  + (size_t)bh * (N_ * HD_);
    const _Float16* Vbh = VTd + (size_t)bh * (HD_ * N_);
    const _Float16* Qbh = Qd  + (size_t)bh * (N_ * HD_);

    const int qbase = qt * 32;
    const f16x4 qf0 = *(const f16x4*)(Qbh + (qbase + col) * HD_ + grp4);
    const f16x4 qf1 = *(const f16x4*)(Qbh + (qbase + 16 + col) * HD_ + grp4);

    const int k0   = wave * 512;                 // this wave's key slice
    const int koff = (k0 + col) * HD_ + grp4;    // K frag base (elements)
    const int voff = col * N_ + k0 + grp4;       // V^T frag base (elements)

    float l0 = 0.f, l1 = 0.f;
    f32x4 o0 = {0.f, 0.f, 0.f, 0.f}, o1 = o0;

    f16x4 kfA[4], vfA[4], kfB[4], vfB[4];
    K2_LOAD(kfA, vfA, 0)
    K2_LOAD(kfB, vfB, 1)

    #pragma unroll
    for (int kt = 0; kt < 8; kt += 2) {
        K2_PROC(kfA, vfA)
        if (kt + 2 < 8) K2_LOAD(kfA, vfA, kt + 2)
        K2_PROC(kfB, vfB)
        if (kt + 3 < 8) K2_LOAD(kfB, vfB, kt + 3)
    }

    // reduce l across the 4 key-groups of this wave
    l0 += __shfl_xor(l0, 16); l0 += __shfl_xor(l0, 32);
    l1 += __shfl_xor(l1, 16); l1 += __shfl_xor(l1, 32);

    // ---- deterministic cross-wave merge --------------------------------
    #pragma unroll
    for (int r = 0; r < 4; ++r) {
        smO[wave][ 0 + grp4 + r][col] = o0[r];
        smO[wave][16 + grp4 + r][col] = o1[r];
    }
    if ((lane >> 4) == 0) {
        smL[wave][ 0 + col] = l0;
        smL[wave][16 + col] = l1;
    }
    __syncthreads();

    {
        const int q = tid >> 3, hp = (tid & 7) * 2;   // 32 q x 8 hd-pairs
        const float ls = smL[0][q] + smL[1][q] + smL[2][q] + smL[3][q];
        const float rl = 1.f / ls;
        float v0 = 0.f, v1 = 0.f;
        #pragma unroll
        for (int w = 0; w < 4; ++w) {
            v0 += smO[w][q][hp];
            v1 += smO[w][q][hp + 1];
        }
        const int b = bh >> 2, h = bh & 3;
        float* dst = O + ((size_t)b * N_ + qbase + q) * DIM_ + h * HD_ + hp;
        dst[0] = v0 * rl;
        dst[1] = v1 * rl;
    }
}

// -------------------------------------------------------------------------
__device__ __forceinline__ float gelu_fast(float v) {
    const float t = v * v;
    const float z = v * fmaf(0.035677408f, t, 0.79788456f);
    const float e = ex2(z * 2.8853900817779268f);   // exp(2z)
    const float r = __builtin_amdgcn_rcpf(e + 1.0f);
    return v * e * r;
}

// -------------------------------------------------------------------------
// Kernel 3 (MFMA, 512 threads, 64 rows/block, grid 256): r12 config
// (best measured). XCD-consumer swizzle kept.
// -------------------------------------------------------------------------
__global__ __launch_bounds__(512) void k3_proj_mlp(
    const float* __restrict__ O,
    const float* __restrict__ Wproj, const float* __restrict__ bproj,
    const float* __restrict__ n2g,   const float* __restrict__ n2b,
    const float* __restrict__ W1,    const float* __restrict__ b1,
    const float* __restrict__ W2,    const float* __restrict__ b2,
    float* __restrict__ out)
{
    union U1 { _Float16 wp[64][68];  _Float16 h[64][68]; };     // 8704 B
    union U2 { _Float16 a[64][68];   _Float16 act[64][136]; };  // 17408 B
    union U3 { _Float16 w1[128][68]; float outs[64][68]; };     // 17408 B
    __shared__ U1 u1;
    __shared__ U2 u2;
    __shared__ U3 u3;
    __shared__ _Float16 W2T[64][136];                           // 17408 B
    __shared__ float    sp [64][68];                            // 17408 B

    const int tid  = threadIdx.x;
    const int lblk = (blockIdx.x & 7) * 32 + (blockIdx.x >> 3);
    const int row0 = lblk * 64;

    #pragma unroll
    for (int i = tid; i < 1024; i += 512) {          // Wproj 64x64
        const float4 w = ((const float4*)Wproj)[i];
        const int e = i * 4, d = e >> 6, c = e & 63;
        u1.wp[c + 0][d] = (_Float16)w.x;
        u1.wp[c + 1][d] = (_Float16)w.y;
        u1.wp[c + 2][d] = (_Float16)w.z;
        u1.wp[c + 3][d] = (_Float16)w.w;
    }
    #pragma unroll
    for (int i = tid; i < 2048; i += 512) {          // W1 64x128
        const float4 w = ((const float4*)W1)[i];
        const int e = i * 4, d = e >> 7, c = e & 127;
        u3.w1[c + 0][d] = (_Float16)w.x;
        u3.w1[c + 1][d] = (_Float16)w.y;
        u3.w1[c + 2][d] = (_Float16)w.z;
        u3.w1[c + 3][d] = (_Float16)w.w;
    }
    #pragma unroll
    for (int i = tid; i < 2048; i += 512) {          // W2 128x64
        const float4 w = ((const float4*)W2)[i];
        const int e = i * 4, d = e >> 6, c = e & 63;
        W2T[c + 0][d] = (_Float16)w.x;
        W2T[c + 1][d] = (_Float16)w.y;
        W2T[c + 2][d] = (_Float16)w.z;
        W2T[c + 3][d] = (_Float16)w.w;
    }
    #pragma unroll
    for (int i = tid; i < 1024; i += 512) {          // O rows -> u2.a
        const float4 v = ((const float4*)(O + (size_t)row0 * DIM_))[i];
        const int e = i * 4, r = e >> 6, c = e & 63;
        f16x4 h4;
        h4[0] = (_Float16)v.x; h4[1] = (_Float16)v.y;
        h4[2] = (_Float16)v.z; h4[3] = (_Float16)v.w;
        *(f16x4*)&u2.a[r][c] = h4;
    }
    __syncthreads();

    const int lane = tid & 63, wave = tid >> 6;
    const int col  = lane & 15;
    const int grp4 = (lane >> 4) * 4;
    const int rt   = wave & 3;
    const int half = wave >> 2;
    const int arow = rt * 16 + col;
    const f32x4 Z = {0.f, 0.f, 0.f, 0.f};

    {
        f16x4 af[4];
        #pragma unroll
        for (int kt = 0; kt < 4; ++kt)
            af[kt] = *(const f16x4*)&u2.a[arow][kt * 16 + grp4];
        #pragma unroll
        for (int cti = 0; cti < 2; ++cti) {
            const int ct = half * 2 + cti;
            f32x4 acc = Z;
            #pragma unroll
            for (int kt = 0; kt < 4; ++kt) {
                const f16x4 bf = *(const f16x4*)&u1.wp[ct * 16 + col][kt * 16 + grp4];
                acc = MFMA16(af[kt], bf, acc);
            }
            const int c = ct * 16 + col;
            const float bias = bproj[c];
            #pragma unroll
            for (int r = 0; r < 4; ++r)
                sp[rt * 16 + grp4 + r][c] = acc[r] + bias;
        }
    }
    __syncthreads();

    {
        const int r = tid >> 4, s = tid & 15;
        const float4 gv = *(const float4*)(n2g + s * 4);
        const float4 bv = *(const float4*)(n2b + s * 4);
        #pragma unroll
        for (int it = 0; it < 2; ++it) {
            const int rl = it * 32 + r;
            const float4 v = *(const float4*)&sp[rl][s * 4];
            float sm = v.x + v.y + v.z + v.w;
            #pragma unroll
            for (int m = 1; m < 16; m <<= 1) sm += __shfl_xor(sm, m);
            const float mu = sm * (1.f / 64.f);
            float4 d4 = make_float4(v.x - mu, v.y - mu, v.z - mu, v.w - mu);
            float qs = d4.x * d4.x + d4.y * d4.y + d4.z * d4.z + d4.w * d4.w;
            #pragma unroll
            for (int m = 1; m < 16; m <<= 1) qs += __shfl_xor(qs, m);
            const float inv = rsqrtf(qs * (1.f / 64.f) + 1e-5f);
            f16x4 ho;
            ho[0] = (_Float16)(d4.x * inv * gv.x + bv.x);
            ho[1] = (_Float16)(d4.y * inv * gv.y + bv.y);
            ho[2] = (_Float16)(d4.z * inv * gv.z + bv.z);
            ho[3] = (_Float16)(d4.w * inv * gv.w + bv.w);
            *(f16x4*)&u1.h[rl][s * 4] = ho;
        }
    }
    __syncthreads();

    {
        f16x4 hf[4];
        #pragma unroll
        for (int kt = 0; kt < 4; ++kt)
            hf[kt] = *(const f16x4*)&u1.h[arow][kt * 16 + grp4];
        #pragma unroll
        for (int cti = 0; cti < 4; ++cti) {
            const int ct = half * 4 + cti;
            f32x4 acc = Z;
            #pragma unroll
            for (int kt = 0; kt < 4; ++kt) {
                const f16x4 bf = *(const f16x4*)&u3.w1[ct * 16 + col][kt * 16 + grp4];
                acc = MFMA16(hf[kt], bf, acc);
            }
            const int c = ct * 16 + col;
            const float bias = b1[c];
            #pragma unroll
            for (int r = 0; r < 4; ++r)
                u2.act[rt * 16 + grp4 + r][c] =
                    (_Float16)gelu_fast(acc[r] + bias);
        }
    }
    __syncthreads();   // act cross-wave + w1 dead (outs aliases it)

    {
        f16x4 pf[8];
        #pragma unroll
        for (int kt = 0; kt < 8; ++kt)
            pf[kt] = *(const f16x4*)&u2.act[arow][kt * 16 + grp4];
        #pragma unroll
        for (int cti = 0; cti < 2; ++cti) {
            const int ct = half * 2 + cti;
            f32x4 acc = Z;
            #pragma unroll
            for (int kt = 0; kt < 8; ++kt) {
                const f16x4 bf = *(const f16x4*)&W2T[ct * 16 + col][kt * 16 + grp4];
                acc = MFMA16(pf[kt], bf, acc);
            }
            const int c = ct * 16 + col;
            const float bias = b2[c];
            #pragma unroll
            for (int r = 0; r < 4; ++r)
                u3.outs[rt * 16 + grp4 + r][c] = acc[r] + bias;
        }
    }
    __syncthreads();

    {
        const int r = tid >> 3, cg = (tid & 7) * 8;
        const float4 a0 = *(const float4*)&u3.outs[r][cg];
        const float4 a1 = *(const float4*)&u3.outs[r][cg + 4];
        const float4 s0 = *(const float4*)&sp[r][cg];
        const float4 s1 = *(const float4*)&sp[r][cg + 4];
        float* op = out + (size_t)(row0 + r) * DIM_ + cg;
        *(float4*)(op)     = make_float4(a0.x + s0.x, a0.y + s0.y,
                                         a0.z + s0.z, a0.w + s0.w);
        *(float4*)(op + 4) = make_float4(a1.x + s1.x, a1.y + s1.y,
                                         a1.z + s1.z, a1.w + s1.w);
    }
}

// -------------------------------------------------------------------------
extern "C" void kernel_launch(void* const* d_in, const int* in_sizes, int n_in,
                              void* d_out, int out_size, void* d_ws, size_t ws_size,
                              hipStream_t stream) {
    const float* x      = (const float*)d_in[0];
    const float* clinic = (const float*)d_in[1];
    const float* n1g    = (const float*)d_in[2];
    const float* n1b    = (const float*)d_in[3];
    const float* n2g    = (const float*)d_in[4];
    const float* n2b    = (const float*)d_in[5];
    const float* Wkv    = (const float*)d_in[6];
    const float* bkv    = (const float*)d_in[7];
    const float* Wq     = (const float*)d_in[8];
    const float* bq     = (const float*)d_in[9];
    const float* Wproj  = (const float*)d_in[10];
    const float* bproj  = (const float*)d_in[11];
    const float* W1     = (const float*)d_in[12];
    const float* b1     = (const float*)d_in[13];
    const float* W2     = (const float*)d_in[14];
    const float* b2     = (const float*)d_in[15];
    float* out = (float*)d_out;

    // workspace: K [BH][N][16], V^T [BH][16][N], Q [BH][N][16] (f16, 2MB ea)
    // + O f32 [B*N][64] (4MB)
    char* ws = (char*)d_ws;
    const size_t SZ = (size_t)B_ * H_ * N_ * HD_;   // 1048576 elements
    _Float16* Kd  = (_Float16*)ws;
    _Float16* VTd = (_Float16*)(ws + 2 * SZ);
    _Float16* Qd  = (_Float16*)(ws + 4 * SZ);
    float*    O   = (float*)   (ws + 6 * SZ);

    k1_ln_qkv<<<NROWS / 64, 512, 0, stream>>>(x, clinic, n1g, n1b, Wkv, bkv,
                                              Wq, bq, Kd, VTd, Qd);
    k2_attn<<<32 * 64, 256, 0, stream>>>(Kd, VTd, Qd, O);
    k3_proj_mlp<<<NROWS / 64, 512, 0, stream>>>(O, Wproj, bproj, n2g, n2b,
                                                W1, b1, W2, b2, out);
}

// Round 16
// 40.100 us; speedup vs baseline: 1.4016x; 1.4016x over previous
//
#include <hip/hip_runtime.h>
#include <hip/hip_bf16.h>
#include <math.h>

#define B_    8
#define N_    2048
#define DIM_  64
#define H_    4
#define HD_   16
#define HID_  128
#define NROWS (B_ * N_)          // 16384
#define KVB   64
#define QSCALE (0.25f * 1.4426950408889634f)   // hd^-0.5 * log2(e)

typedef float    f32x4 __attribute__((ext_vector_type(4)));
typedef __fp16   hfx2  __attribute__((ext_vector_type(2)));
typedef _Float16 f16x4 __attribute__((ext_vector_type(4)));
typedef _Float16 f16x8 __attribute__((ext_vector_type(8)));

#define MFMA16(a, b, c) __builtin_amdgcn_mfma_f32_16x16x16f16((a), (b), (c), 0, 0, 0)

__device__ __forceinline__ float ex2(float x) {
#if __has_builtin(__builtin_amdgcn_exp2f)
    return __builtin_amdgcn_exp2f(x);
#else
    return exp2f(x);
#endif
}

// -------------------------------------------------------------------------
// Kernel 1 (MFMA, 512 threads): XCD-producer swizzle (batch b -> XCD b).
// Round-12 config (best measured).
// -------------------------------------------------------------------------
__global__ __launch_bounds__(512) void k1_ln_qkv(
    const float* __restrict__ x, const float* __restrict__ clinic,
    const float* __restrict__ n1g, const float* __restrict__ n1b,
    const float* __restrict__ Wkv, const float* __restrict__ bkv,
    const float* __restrict__ Wq,  const float* __restrict__ bq,
    _Float16* __restrict__ Kd, _Float16* __restrict__ VTd,
    _Float16* __restrict__ Qd)
{
    __shared__ _Float16 WkvT[128][68];   // [col][k]
    __shared__ _Float16 WqT [64][68];
    __shared__ _Float16 xnT [64][68];    // [row][k]
    __shared__ _Float16 cnT [64][68];

    const int tid  = threadIdx.x;
    const int lblk = (blockIdx.x & 7) * 32 + (blockIdx.x >> 3);
    const int row0 = lblk * 64;

    #pragma unroll
    for (int i = tid; i < 2048; i += 512) {          // Wkv 64x128
        const float4 w = ((const float4*)Wkv)[i];
        const int e = i * 4, d = e >> 7, c = e & 127;
        WkvT[c + 0][d] = (_Float16)w.x;
        WkvT[c + 1][d] = (_Float16)w.y;
        WkvT[c + 2][d] = (_Float16)w.z;
        WkvT[c + 3][d] = (_Float16)w.w;
    }
    #pragma unroll
    for (int i = tid; i < 1024; i += 512) {          // Wq 64x64
        const float4 w = ((const float4*)Wq)[i];
        const int e = i * 4, d = e >> 6, c = e & 63;
        WqT[c + 0][d] = (_Float16)w.x;
        WqT[c + 1][d] = (_Float16)w.y;
        WqT[c + 2][d] = (_Float16)w.z;
        WqT[c + 3][d] = (_Float16)w.w;
    }

    {
        const int r = tid >> 4, s = tid & 15;
        const float4 gv = *(const float4*)(n1g + s * 4);
        const float4 bv = *(const float4*)(n1b + s * 4);
        #pragma unroll
        for (int it = 0; it < 2; ++it) {
            const int rl = it * 32 + r;
            const int rg = row0 + rl;
            float4 xv = *(const float4*)(x      + (size_t)rg * DIM_ + s * 4);
            float4 cv = *(const float4*)(clinic + (size_t)rg * DIM_ + s * 4);

            float xs = xv.x + xv.y + xv.z + xv.w;
            float cs = cv.x + cv.y + cv.z + cv.w;
            #pragma unroll
            for (int m = 1; m < 16; m <<= 1) {
                xs += __shfl_xor(xs, m);
                cs += __shfl_xor(cs, m);
            }
            const float xmu = xs * (1.f / 64.f);
            const float cmu = cs * (1.f / 64.f);
            float4 xd = make_float4(xv.x - xmu, xv.y - xmu, xv.z - xmu, xv.w - xmu);
            float4 cd = make_float4(cv.x - cmu, cv.y - cmu, cv.z - cmu, cv.w - cmu);

            float xq = xd.x * xd.x + xd.y * xd.y + xd.z * xd.z + xd.w * xd.w;
            float cq = cd.x * cd.x + cd.y * cd.y + cd.z * cd.z + cd.w * cd.w;
            #pragma unroll
            for (int m = 1; m < 16; m <<= 1) {
                xq += __shfl_xor(xq, m);
                cq += __shfl_xor(cq, m);
            }
            const float xinv = rsqrtf(xq * (1.f / 64.f) + 1e-5f);
            const float cinv = rsqrtf(cq * (1.f / 64.f) + 1e-5f);

            f16x4 xo, co;
            xo[0] = (_Float16)(xd.x * xinv * gv.x + bv.x);
            xo[1] = (_Float16)(xd.y * xinv * gv.y + bv.y);
            xo[2] = (_Float16)(xd.z * xinv * gv.z + bv.z);
            xo[3] = (_Float16)(xd.w * xinv * gv.w + bv.w);
            co[0] = (_Float16)(cd.x * cinv * gv.x + bv.x);
            co[1] = (_Float16)(cd.y * cinv * gv.y + bv.y);
            co[2] = (_Float16)(cd.z * cinv * gv.z + bv.z);
            co[3] = (_Float16)(cd.w * cinv * gv.w + bv.w);
            *(f16x4*)&xnT[rl][s * 4] = xo;
            *(f16x4*)&cnT[rl][s * 4] = co;
        }
    }
    __syncthreads();

    const int lane = tid & 63, wave = tid >> 6;
    const int col  = lane & 15;
    const int grp4 = (lane >> 4) * 4;
    const int rt   = wave & 3;
    const int half = wave >> 2;
    const int arow = rt * 16 + col;
    const f32x4 Z = {0.f, 0.f, 0.f, 0.f};

    f16x4 ax[4], ac[4];
    #pragma unroll
    for (int kt = 0; kt < 4; ++kt) {
        ax[kt] = *(const f16x4*)&xnT[arow][kt * 16 + grp4];
        ac[kt] = *(const f16x4*)&cnT[arow][kt * 16 + grp4];
    }

    const int rg0 = row0 + rt * 16 + grp4;
    const int b   = rg0 >> 11;
    const int n0  = rg0 & (N_ - 1);

    #pragma unroll
    for (int cti = 0; cti < 4; ++cti) {
        const int ct = half * 4 + cti;
        f32x4 acc = Z;
        #pragma unroll
        for (int kt = 0; kt < 4; ++kt) {
            const f16x4 bf = *(const f16x4*)&WkvT[ct * 16 + col][kt * 16 + grp4];
            acc = MFMA16(ax[kt], bf, acc);
        }
        const int c = ct * 16 + col;
        const float bias = bkv[c];
        const int hh = (c >> 4) & 3, dd = c & 15;
        if (c & 64) {
            f16x4 v4;
            #pragma unroll
            for (int r = 0; r < 4; ++r) v4[r] = (_Float16)(acc[r] + bias);
            *(f16x4*)(VTd + (((size_t)(b * H_ + hh)) * HD_ + dd) * N_ + n0) = v4;
        } else {
            #pragma unroll
            for (int r = 0; r < 4; ++r)
                Kd[(((size_t)(b * H_ + hh)) * N_ + n0 + r) * HD_ + dd] =
                    (_Float16)(acc[r] + bias);
        }
    }
    #pragma unroll
    for (int cti = 0; cti < 2; ++cti) {
        const int ct = half * 2 + cti;
        f32x4 acc = Z;
        #pragma unroll
        for (int kt = 0; kt < 4; ++kt) {
            const f16x4 bf = *(const f16x4*)&WqT[ct * 16 + col][kt * 16 + grp4];
            acc = MFMA16(ac[kt], bf, acc);
        }
        const int c = ct * 16 + col;
        const float bias = bq[c];
        const int hh = c >> 4, dd = c & 15;
        #pragma unroll
        for (int r = 0; r < 4; ++r)
            Qd[(((size_t)(b * H_ + hh)) * N_ + n0 + r) * HD_ + dd] =
                (_Float16)((acc[r] + bias) * QSCALE);
    }
}

// -------------------------------------------------------------------------
// Kernel 2: pure-register MFMA flash attention, 2-process-deep prefetch.
// Round-12 config (best measured): 4 q-frags/wave, grid 1024, spill-safe
// macros, XCD producer/consumer alignment, v_exp_f32 softmax.
// -------------------------------------------------------------------------
#define K2_LOAD(KF, VF, T)                                                   \
    {                                                                        \
        _Pragma("unroll")                                                    \
        for (int sb = 0; sb < 4; ++sb) {                                     \
            KF[sb] = *(const f16x4*)(Kbh + koff + (T) * (KVB * HD_) +        \
                                     sb * (16 * HD_));                       \
            VF[sb] = *(const f16x4*)(Vbh + voff + (T) * KVB + sb * 16);      \
        }                                                                    \
    }

#define K2_PROC(KF, VF)                                                      \
    {                                                                        \
        const f32x4 Z = {0.f, 0.f, 0.f, 0.f};                                \
        _Pragma("unroll")                                                    \
        for (int qp = 0; qp < 4; ++qp) {                                     \
            f32x4 s[4];                                                      \
            _Pragma("unroll")                                                \
            for (int sb = 0; sb < 4; ++sb)                                   \
                s[sb] = MFMA16(KF[sb], qf[qp], Z);                           \
            float pl = 0.f;                                                  \
            f16x4 pf[4];                                                     \
            _Pragma("unroll")                                                \
            for (int sb = 0; sb < 4; ++sb) {                                 \
                const float a0 = ex2(s[sb][0]), a1 = ex2(s[sb][1]);          \
                const float a2 = ex2(s[sb][2]), a3 = ex2(s[sb][3]);          \
                pl += (a0 + a1) + (a2 + a3);                                 \
                const hfx2 lo = __builtin_amdgcn_cvt_pkrtz(a0, a1);          \
                const hfx2 hi = __builtin_amdgcn_cvt_pkrtz(a2, a3);          \
                pf[sb] = (f16x4){(_Float16)lo[0], (_Float16)lo[1],           \
                                 (_Float16)hi[0], (_Float16)hi[1]};          \
            }                                                                \
            if (qp == 0) l0 += pl; else if (qp == 1) l1 += pl;               \
            else if (qp == 2) l2 += pl; else l3 += pl;                       \
            f32x4& o = (qp == 0) ? o0 : (qp == 1) ? o1 :                     \
                       (qp == 2) ? o2 : o3;                                  \
            _Pragma("unroll")                                                \
            for (int sb = 0; sb < 4; ++sb)                                   \
                o = MFMA16(pf[sb], VF[sb], o);                               \
        }                                                                    \
    }

__global__ __launch_bounds__(256, 4) void k2_attn(
    const _Float16* __restrict__ Kd, const _Float16* __restrict__ VTd,
    const _Float16* __restrict__ Qd, float* __restrict__ O)
{
    __shared__ float smO[4][64][18];   // merge: [wave][q][hd+pad]
    __shared__ float smL[4][64];

    const int tid  = threadIdx.x;
    const int lane = tid & 63;
    const int wave = tid >> 6;
    const int col  = lane & 15;
    const int grp4 = (lane >> 4) * 4;

    // consumer swizzle: XCD x handles bh in [4x, 4x+4) = batch x
    const int wg = (blockIdx.x & 7) * 128 + (blockIdx.x >> 3);
    const int bh = wg >> 5;        // 0..31
    const int qt = wg & 31;        // 0..31

    const _Float16* Kbh = Kd  + (size_t)bh * (N_ * HD_);
    const _Float16* Vbh = VTd + (size_t)bh * (HD_ * N_);
    const _Float16* Qbh = Qd  + (size_t)bh * (N_ * HD_);

    const int qbase = qt * 64;
    f16x4 qf[4];
    #pragma unroll
    for (int qp = 0; qp < 4; ++qp)
        qf[qp] = *(const f16x4*)(Qbh + (qbase + qp * 16 + col) * HD_ + grp4);

    const int k0   = wave * 512;                 // this wave's key slice
    const int koff = (k0 + col) * HD_ + grp4;    // K frag base (elements)
    const int voff = col * N_ + k0 + grp4;       // V^T frag base (elements)

    float l0 = 0.f, l1 = 0.f, l2 = 0.f, l3 = 0.f;
    f32x4 o0 = {0.f, 0.f, 0.f, 0.f}, o1 = o0, o2 = o0, o3 = o0;

    f16x4 kfA[4], vfA[4], kfB[4], vfB[4];
    K2_LOAD(kfA, vfA, 0)
    K2_LOAD(kfB, vfB, 1)

    #pragma unroll
    for (int kt = 0; kt < 8; kt += 2) {
        K2_PROC(kfA, vfA)
        if (kt + 2 < 8) K2_LOAD(kfA, vfA, kt + 2)
        K2_PROC(kfB, vfB)
        if (kt + 3 < 8) K2_LOAD(kfB, vfB, kt + 3)
    }

    // reduce l across the 4 key-groups of this wave
    l0 += __shfl_xor(l0, 16); l0 += __shfl_xor(l0, 32);
    l1 += __shfl_xor(l1, 16); l1 += __shfl_xor(l1, 32);
    l2 += __shfl_xor(l2, 16); l2 += __shfl_xor(l2, 32);
    l3 += __shfl_xor(l3, 16); l3 += __shfl_xor(l3, 32);

    // ---- deterministic cross-wave merge --------------------------------
    #pragma unroll
    for (int r = 0; r < 4; ++r) {
        smO[wave][ 0 + grp4 + r][col] = o0[r];
        smO[wave][16 + grp4 + r][col] = o1[r];
        smO[wave][32 + grp4 + r][col] = o2[r];
        smO[wave][48 + grp4 + r][col] = o3[r];
    }
    if ((lane >> 4) == 0) {
        smL[wave][ 0 + col] = l0;
        smL[wave][16 + col] = l1;
        smL[wave][32 + col] = l2;
        smL[wave][48 + col] = l3;
    }
    __syncthreads();

    {
        const int q = tid >> 2, h4 = (tid & 3) * 4;   // 64 q x 4 hd-quads
        const float ls = smL[0][q] + smL[1][q] + smL[2][q] + smL[3][q];
        const float rl = 1.f / ls;
        float v[4];
        #pragma unroll
        for (int j = 0; j < 4; ++j)
            v[j] = (smO[0][q][h4 + j] + smO[1][q][h4 + j] +
                    smO[2][q][h4 + j] + smO[3][q][h4 + j]) * rl;
        const int b = bh >> 2, h = bh & 3;
        float* dst = O + ((size_t)b * N_ + qbase + q) * DIM_ + h * HD_ + h4;
        *(float4*)dst = make_float4(v[0], v[1], v[2], v[3]);
    }
}

// -------------------------------------------------------------------------
__device__ __forceinline__ float gelu_fast(float v) {
    const float t = v * v;
    const float z = v * fmaf(0.035677408f, t, 0.79788456f);
    const float e = ex2(z * 2.8853900817779268f);   // exp(2z)
    const float r = __builtin_amdgcn_rcpf(e + 1.0f);
    return v * e * r;
}

// -------------------------------------------------------------------------
// Kernel 3 (MFMA, 512 threads): XCD-consumer swizzle. Round-12 config.
// -------------------------------------------------------------------------
__global__ __launch_bounds__(512) void k3_proj_mlp(
    const float* __restrict__ O,
    const float* __restrict__ Wproj, const float* __restrict__ bproj,
    const float* __restrict__ n2g,   const float* __restrict__ n2b,
    const float* __restrict__ W1,    const float* __restrict__ b1,
    const float* __restrict__ W2,    const float* __restrict__ b2,
    float* __restrict__ out)
{
    union U1 { _Float16 wp[64][68];  _Float16 h[64][68]; };     // 8704 B
    union U2 { _Float16 a[64][68];   _Float16 act[64][136]; };  // 17408 B
    union U3 { _Float16 w1[128][68]; float outs[64][68]; };     // 17408 B
    __shared__ U1 u1;
    __shared__ U2 u2;
    __shared__ U3 u3;
    __shared__ _Float16 W2T[64][136];                           // 17408 B
    __shared__ float    sp [64][68];                            // 17408 B

    const int tid  = threadIdx.x;
    const int lblk = (blockIdx.x & 7) * 32 + (blockIdx.x >> 3);
    const int row0 = lblk * 64;

    #pragma unroll
    for (int i = tid; i < 1024; i += 512) {          // Wproj 64x64
        const float4 w = ((const float4*)Wproj)[i];
        const int e = i * 4, d = e >> 6, c = e & 63;
        u1.wp[c + 0][d] = (_Float16)w.x;
        u1.wp[c + 1][d] = (_Float16)w.y;
        u1.wp[c + 2][d] = (_Float16)w.z;
        u1.wp[c + 3][d] = (_Float16)w.w;
    }
    #pragma unroll
    for (int i = tid; i < 2048; i += 512) {          // W1 64x128
        const float4 w = ((const float4*)W1)[i];
        const int e = i * 4, d = e >> 7, c = e & 127;
        u3.w1[c + 0][d] = (_Float16)w.x;
        u3.w1[c + 1][d] = (_Float16)w.y;
        u3.w1[c + 2][d] = (_Float16)w.z;
        u3.w1[c + 3][d] = (_Float16)w.w;
    }
    #pragma unroll
    for (int i = tid; i < 2048; i += 512) {          // W2 128x64
        const float4 w = ((const float4*)W2)[i];
        const int e = i * 4, d = e >> 6, c = e & 63;
        W2T[c + 0][d] = (_Float16)w.x;
        W2T[c + 1][d] = (_Float16)w.y;
        W2T[c + 2][d] = (_Float16)w.z;
        W2T[c + 3][d] = (_Float16)w.w;
    }
    #pragma unroll
    for (int i = tid; i < 1024; i += 512) {          // O rows -> u2.a
        const float4 v = ((const float4*)(O + (size_t)row0 * DIM_))[i];
        const int e = i * 4, r = e >> 6, c = e & 63;
        f16x4 h4;
        h4[0] = (_Float16)v.x; h4[1] = (_Float16)v.y;
        h4[2] = (_Float16)v.z; h4[3] = (_Float16)v.w;
        *(f16x4*)&u2.a[r][c] = h4;
    }
    __syncthreads();

    const int lane = tid & 63, wave = tid >> 6;
    const int col  = lane & 15;
    const int grp4 = (lane >> 4) * 4;
    const int rt   = wave & 3;
    const int half = wave >> 2;
    const int arow = rt * 16 + col;
    const f32x4 Z = {0.f, 0.f, 0.f, 0.f};

    {
        f16x4 af[4];
        #pragma unroll
        for (int kt = 0; kt < 4; ++kt)
            af[kt] = *(const f16x4*)&u2.a[arow][kt * 16 + grp4];
        #pragma unroll
        for (int cti = 0; cti < 2; ++cti) {
            const int ct = half * 2 + cti;
            f32x4 acc = Z;
            #pragma unroll
            for (int kt = 0; kt < 4; ++kt) {
                const f16x4 bf = *(const f16x4*)&u1.wp[ct * 16 + col][kt * 16 + grp4];
                acc = MFMA16(af[kt], bf, acc);
            }
            const int c = ct * 16 + col;
            const float bias = bproj[c];
            #pragma unroll
            for (int r = 0; r < 4; ++r)
                sp[rt * 16 + grp4 + r][c] = acc[r] + bias;
        }
    }
    __syncthreads();

    {
        const int r = tid >> 4, s = tid & 15;
        const float4 gv = *(const float4*)(n2g + s * 4);
        const float4 bv = *(const float4*)(n2b + s * 4);
        #pragma unroll
        for (int it = 0; it < 2; ++it) {
            const int rl = it * 32 + r;
            const float4 v = *(const float4*)&sp[rl][s * 4];
            float sm = v.x + v.y + v.z + v.w;
            #pragma unroll
            for (int m = 1; m < 16; m <<= 1) sm += __shfl_xor(sm, m);
            const float mu = sm * (1.f / 64.f);
            float4 d4 = make_float4(v.x - mu, v.y - mu, v.z - mu, v.w - mu);
            float qs = d4.x * d4.x + d4.y * d4.y + d4.z * d4.z + d4.w * d4.w;
            #pragma unroll
            for (int m = 1; m < 16; m <<= 1) qs += __shfl_xor(qs, m);
            const float inv = rsqrtf(qs * (1.f / 64.f) + 1e-5f);
            f16x4 ho;
            ho[0] = (_Float16)(d4.x * inv * gv.x + bv.x);
            ho[1] = (_Float16)(d4.y * inv * gv.y + bv.y);
            ho[2] = (_Float16)(d4.z * inv * gv.z + bv.z);
            ho[3] = (_Float16)(d4.w * inv * gv.w + bv.w);
            *(f16x4*)&u1.h[rl][s * 4] = ho;
        }
    }
    __syncthreads();

    {
        f16x4 hf[4];
        #pragma unroll
        for (int kt = 0; kt < 4; ++kt)
            hf[kt] = *(const f16x4*)&u1.h[arow][kt * 16 + grp4];
        #pragma unroll
        for (int cti = 0; cti < 4; ++cti) {
            const int ct = half * 4 + cti;
            f32x4 acc = Z;
            #pragma unroll
            for (int kt = 0; kt < 4; ++kt) {
                const f16x4 bf = *(const f16x4*)&u3.w1[ct * 16 + col][kt * 16 + grp4];
                acc = MFMA16(hf[kt], bf, acc);
            }
            const int c = ct * 16 + col;
            const float bias = b1[c];
            #pragma unroll
            for (int r = 0; r < 4; ++r)
                u2.act[rt * 16 + grp4 + r][c] =
                    (_Float16)gelu_fast(acc[r] + bias);
        }
    }
    __syncthreads();   // act cross-wave + w1 dead (outs aliases it)

    {
        f16x4 pf[8];
        #pragma unroll
        for (int kt = 0; kt < 8; ++kt)
            pf[kt] = *(const f16x4*)&u2.act[arow][kt * 16 + grp4];
        #pragma unroll
        for (int cti = 0; cti < 2; ++cti) {
            const int ct = half * 2 + cti;
            f32x4 acc = Z;
            #pragma unroll
            for (int kt = 0; kt < 8; ++kt) {
                const f16x4 bf = *(const f16x4*)&W2T[ct * 16 + col][kt * 16 + grp4];
                acc = MFMA16(pf[kt], bf, acc);
            }
            const int c = ct * 16 + col;
            const float bias = b2[c];
            #pragma unroll
            for (int r = 0; r < 4; ++r)
                u3.outs[rt * 16 + grp4 + r][c] = acc[r] + bias;
        }
    }
    __syncthreads();

    {
        const int r = tid >> 3, cg = (tid & 7) * 8;
        const float4 a0 = *(const float4*)&u3.outs[r][cg];
        const float4 a1 = *(const float4*)&u3.outs[r][cg + 4];
        const float4 s0 = *(const float4*)&sp[r][cg];
        const float4 s1 = *(const float4*)&sp[r][cg + 4];
        float* op = out + (size_t)(row0 + r) * DIM_ + cg;
        *(float4*)(op)     = make_float4(a0.x + s0.x, a0.y + s0.y,
                                         a0.z + s0.z, a0.w + s0.w);
        *(float4*)(op + 4) = make_float4(a1.x + s1.x, a1.y + s1.y,
                                         a1.z + s1.z, a1.w + s1.w);
    }
}

// -------------------------------------------------------------------------
extern "C" void kernel_launch(void* const* d_in, const int* in_sizes, int n_in,
                              void* d_out, int out_size, void* d_ws, size_t ws_size,
                              hipStream_t stream) {
    const float* x      = (const float*)d_in[0];
    const float* clinic = (const float*)d_in[1];
    const float* n1g    = (const float*)d_in[2];
    const float* n1b    = (const float*)d_in[3];
    const float* n2g    = (const float*)d_in[4];
    const float* n2b    = (const float*)d_in[5];
    const float* Wkv    = (const float*)d_in[6];
    const float* bkv    = (const float*)d_in[7];
    const float* Wq     = (const float*)d_in[8];
    const float* bq     = (const float*)d_in[9];
    const float* Wproj  = (const float*)d_in[10];
    const float* bproj  = (const float*)d_in[11];
    const float* W1     = (const float*)d_in[12];
    const float* b1     = (const float*)d_in[13];
    const float* W2     = (const float*)d_in[14];
    const float* b2     = (const float*)d_in[15];
    float* out = (float*)d_out;

    // workspace: K [BH][N][16], V^T [BH][16][N], Q [BH][N][16] (f16, 2MB ea)
    // + O f32 [B*N][64] (4MB)
    char* ws = (char*)d_ws;
    const size_t SZ = (size_t)B_ * H_ * N_ * HD_;   // 1048576 elements
    _Float16* Kd  = (_Float16*)ws;
    _Float16* VTd = (_Float16*)(ws + 2 * SZ);
    _Float16* Qd  = (_Float16*)(ws + 4 * SZ);
    float*    O   = (float*)   (ws + 6 * SZ);

    k1_ln_qkv<<<NROWS / 64, 512, 0, stream>>>(x, clinic, n1g, n1b, Wkv, bkv,
                                              Wq, bq, Kd, VTd, Qd);
    k2_attn<<<32 * 32, 256, 0, stream>>>(Kd, VTd, Qd, O);
    k3_proj_mlp<<<NROWS / 64, 512, 0, stream>>>(O, Wproj, bproj, n2g, n2b,
                                                W1, b1, W2, b2, out);
}